// Round 1
// baseline (111.493 us; speedup 1.0000x reference)
//
#include <hip/hip_runtime.h>
#include <math.h>

// Problem constants (T, B, D) = (1024, 16, 1024)
#define T_DIM 1024
#define C_DIM 16384            // B*D columns, each an independent scan
#define WAVES 16               // waves per block
#define BLOCK_T (WAVES * 64)   // 1024 threads
#define L_CHUNK (T_DIM / WAVES) // 64 rows per wave

// Each block: 64 columns (one lane per column), T split across 16 waves.
// Single pass: load chunk to regs -> local scan -> LDS carry exchange ->
// per-wave prefix -> apply + store. One read + one write per element.
__global__ __launch_bounds__(BLOCK_T, 4)
void pli_scan_kernel(const float* __restrict__ x,
                     const float* __restrict__ beta_p,
                     float* __restrict__ out) {
    const int lane = threadIdx.x & 63;
    const int w    = threadIdx.x >> 6;           // wave id = T-chunk id
    const int col  = (blockIdx.x << 6) + lane;   // this lane's column

    // beta = sigmoid(beta_param), computed per-thread (broadcast load, cheap)
    const float beta = 1.0f / (1.0f + expf(-beta_p[0]));

    const size_t base = (size_t)(w * L_CHUNK) * C_DIM + col;
    const float* xp = x + base;

    // Stage the chunk in registers: 64 independent coalesced loads (256B/instr)
    float v[L_CHUNK];
#pragma unroll
    for (int t = 0; t < L_CHUNK; ++t) {
        v[t] = xp[(size_t)t * C_DIM];
    }

    // Local (zero-initialized) scan in place: v[t] = sum_{u<=t} beta^(t-u) x[u]
    float run = 0.0f;
#pragma unroll
    for (int t = 0; t < L_CHUNK; ++t) {
        run = fmaf(run, beta, v[t]);
        v[t] = run;
    }

    // Exchange per-chunk carries (value of local scan at chunk end)
    __shared__ float carry[WAVES][64];
    carry[w][lane] = run;
    __syncthreads();

    // beta^L via repeated squaring: L=64 -> 6 squarings
    float bL = beta;
#pragma unroll
    for (int i = 0; i < 6; ++i) bL *= bL;

    // Prefix for this chunk: Y_prev = full scan value at row (w*L - 1)
    // Y_v = carry_v + beta^L * Y_{v-1}; iterate v = 0..w-1 (wave-uniform count)
    float Y = 0.0f;
    for (int u = 0; u < w; ++u) {
        Y = fmaf(Y, bL, carry[u][lane]);
    }

    // y[s+t] = local[t] + beta^(t+1) * Y_prev
    float m = beta * Y;
    float* op = out + base;
#pragma unroll
    for (int t = 0; t < L_CHUNK; ++t) {
        op[(size_t)t * C_DIM] = v[t] + m;
        m *= beta;
    }
}

extern "C" void kernel_launch(void* const* d_in, const int* in_sizes, int n_in,
                              void* d_out, int out_size, void* d_ws, size_t ws_size,
                              hipStream_t stream) {
    const float* x      = (const float*)d_in[0];   // [T, B, D] fp32
    const float* beta_p = (const float*)d_in[1];   // scalar fp32
    float* out          = (float*)d_out;           // [T, B, D] fp32

    dim3 grid(C_DIM / 64);   // 256 blocks, one per CU
    dim3 block(BLOCK_T);     // 1024 threads = 16 waves
    hipLaunchKernelGGL(pli_scan_kernel, grid, block, 0, stream, x, beta_p, out);
}